// Round 16
// baseline (36.401 us; speedup 1.0000x reference)
//
#include <hip/hip_runtime.h>
#include <math.h>

#define Bdim 64
#define Tdim 512
#define Sdim 400
#define Hdim 768
#define Ldim 9

#define QWIN 130        // tokens projected per block: 128 + 2 overlap (len<=3)
#define LPROJ_ROWS 132  // LDS tile rows (padded)

// ---------------------------------------------------------------------------
// DPP 64-lane sum (row_shr 1/2/4/8 + row_bcast 15/31), result in lane 63.
// ---------------------------------------------------------------------------
template <int CTRL>
__device__ __forceinline__ float dpp_add(float x) {
  int y = __builtin_amdgcn_update_dpp(0, __float_as_int(x), CTRL, 0xF, 0xF, false);
  return x + __int_as_float(y);
}
__device__ __forceinline__ float wave_sum63(float x) {
  x = dpp_add<0x111>(x);
  x = dpp_add<0x112>(x);
  x = dpp_add<0x114>(x);
  x = dpp_add<0x118>(x);
  x = dpp_add<0x142>(x);
  x = dpp_add<0x143>(x);
  return x;  // lane 63 = sum of all 64 lanes
}

// ---------------------------------------------------------------------------
// Single fused kernel: 256 blocks = (batch row b, quarter). 512 threads.
//  A: per-row scans in LDS (p2t, wstart, nvalid)
//  B: project window tokens q in [part*128, min(+QWIN, nvalid)) into LDS.
//     ALL 8 waves: wave w owns tokens q0+w, q0+w+8, ... (stride 8), computes
//     all 9 logits with a 108-float register W fragment (launch_bounds(512,1)
//     -> ~256 VGPR budget; R5's (256,3) 85-VGPR cap was what forced silent
//     per-token rematerialization). Depth-2 ping-pong, named buffers.
//  C: words with wstart-bucket == part: mean from LDS, +bias, argmax -> out,
//     NLL -> 256 block-atomics; last block finalizes loss (single launch).
// Bytes are L3-resident in steady state (R9->R14: 22 MB <-> 1.6 us, ~14 TB/s
// marginal) -- this round attacks structure, not bytes.
// ---------------------------------------------------------------------------
__global__ __launch_bounds__(512, 1) void fused_kernel(
    const float* __restrict__ enc, const float* __restrict__ W,
    const float* __restrict__ bias, const int* __restrict__ attn,
    const int* __restrict__ ids_lens, const int* __restrict__ label_ids,
    float* __restrict__ out, float* __restrict__ accum,
    unsigned* __restrict__ counter) {
  int blk = blockIdx.x;
  int b = blk >> 2;
  int part = blk & 3;
  int q0 = part << 7;
  int tid = threadIdx.x;
  int lane = tid & 63, wid = tid >> 6;

  __shared__ int p2t[Tdim];
  __shared__ int wst[Sdim];
  __shared__ float lproj[LPROJ_ROWS][12];
  __shared__ int wsum[8];
  __shared__ int totsm;
  __shared__ float ssm[8], csm[8];

  // ================= phase A: scans =================
  int m = attn[b * Tdim + tid];
  int x = m;
#pragma unroll
  for (int off = 1; off < 64; off <<= 1) {
    int v = __shfl_up(x, off, 64);
    if (lane >= off) x += v;
  }
  if (lane == 63) wsum[wid] = x;
  __syncthreads();
  if (tid < 8) {
    int s = wsum[tid], y = s;
#pragma unroll
    for (int off = 1; off < 8; off <<= 1) {
      int v = __shfl_up(y, off, 64);
      if (tid >= off) y += v;
    }
    wsum[tid] = y - s;
    if (tid == 7) totsm = y;
  }
  __syncthreads();
  x += wsum[wid];
  if (m) p2t[x - 1] = tid;  // q-th valid token -> physical position
  int nv = totsm;
  __syncthreads();  // p2t written; wsum reusable

  int len = (tid < Sdim) ? ids_lens[b * Sdim + tid] : 0;
  int x2 = len;
#pragma unroll
  for (int off = 1; off < 64; off <<= 1) {
    int v = __shfl_up(x2, off, 64);
    if (lane >= off) x2 += v;
  }
  if (lane == 63) wsum[wid] = x2;
  __syncthreads();
  if (tid < 8) {
    int s = wsum[tid], y = s;
#pragma unroll
    for (int off = 1; off < 8; off <<= 1) {
      int v = __shfl_up(y, off, 64);
      if (tid >= off) y += v;
    }
    wsum[tid] = y - s;
  }
  __syncthreads();
  x2 += wsum[wid];
  if (tid < Sdim) wst[tid] = x2 - len;  // exclusive prefix
  __syncthreads();

  // ================= phase B: project this block's token window =================
  {
    int lim = q0 + QWIN;
    if (lim > nv) lim = nv;
    // wave wid owns tokens q0+wid, q0+wid+8, ... ; tc = count
    int tc = lim - q0 - wid;
    tc = (tc > 0) ? ((tc + 7) >> 3) : 0;

    if (tc > 0) {
      // 108-float register W fragment: h = 4*lane + 256*c + j, all 9 logits
      float wf[3][4][Ldim];
#pragma unroll
      for (int c = 0; c < 3; ++c)
#pragma unroll
        for (int j = 0; j < 4; ++j) {
          int h = 4 * lane + 256 * c + j;
#pragma unroll
          for (int l = 0; l < Ldim; ++l) wf[c][j][l] = W[(size_t)h * Ldim + l];
        }
      const float4* encb = (const float4*)enc + (size_t)(b << 9) * (Hdim / 4);

      float4 A0, A1, A2, B0, B1, B2;
#define LDK(V0, V1, V2, K)                                                 \
  {                                                                        \
    int t_ = p2t[q0 + wid + 8 * (K)];                                      \
    const float4* r_ = encb + (size_t)t_ * (Hdim / 4);                     \
    V0 = r_[lane]; V1 = r_[lane + 64]; V2 = r_[lane + 128];                \
  }
#define PRK(V0, V1, V2, K)                                                 \
  {                                                                        \
    float dd[Ldim];                                                        \
    _Pragma("unroll") for (int l = 0; l < Ldim; ++l) {                     \
      dd[l] = V0.x * wf[0][0][l] + V0.y * wf[0][1][l] +                    \
              V0.z * wf[0][2][l] + V0.w * wf[0][3][l] +                    \
              V1.x * wf[1][0][l] + V1.y * wf[1][1][l] +                    \
              V1.z * wf[1][2][l] + V1.w * wf[1][3][l] +                    \
              V2.x * wf[2][0][l] + V2.y * wf[2][1][l] +                    \
              V2.z * wf[2][2][l] + V2.w * wf[2][3][l];                     \
      dd[l] = wave_sum63(dd[l]);                                           \
    }                                                                      \
    if (lane == 63) {                                                      \
      float* dst = lproj[wid + 8 * (K)];                                   \
      _Pragma("unroll") for (int l = 0; l < Ldim; ++l) dst[l] = dd[l];     \
    }                                                                      \
  }
      LDK(A0, A1, A2, 0)
      if (tc > 1) LDK(B0, B1, B2, 1)
      int k = 0;
      for (; k + 2 < tc; k += 2) {
        PRK(A0, A1, A2, k)
        LDK(A0, A1, A2, k + 2)
        PRK(B0, B1, B2, k + 1)
        if (k + 3 < tc) LDK(B0, B1, B2, k + 3)
      }
      PRK(A0, A1, A2, k)
      if (k + 1 < tc) PRK(B0, B1, B2, k + 1)
#undef LDK
#undef PRK
    }
  }
  __syncthreads();

  // ================= phase C: this block's words =================
  float nll = 0.0f, cnt = 0.0f;
  if (tid < Sdim) {
    int st = wst[tid];
    int stc = (st > 511) ? 511 : st;
    if ((stc >> 7) == part) {  // this block owns word tid
      int bs = b * Sdim + tid;
      float sum[Ldim];
#pragma unroll
      for (int l = 0; l < Ldim; ++l) sum[l] = 0.0f;
      if (len > 0) {
        for (int j = 0; j < len; ++j) {
          int q = st + j;
          if (q >= nv) break;
          const float* pr = lproj[q - q0];
#pragma unroll
          for (int l = 0; l < Ldim; ++l) sum[l] += pr[l];
        }
      }
      float inv = (len > 0) ? 1.0f / (float)len : 0.0f;
      float lg[Ldim];
#pragma unroll
      for (int l = 0; l < Ldim; ++l) lg[l] = sum[l] * inv + bias[l];

      int amax = 0;
      float mx = lg[0];
#pragma unroll
      for (int l = 1; l < Ldim; ++l)
        if (lg[l] > mx) { mx = lg[l]; amax = l; }
      out[1 + bs] = (float)amax;

      if (len > 0) {
        float se = 0.0f;
#pragma unroll
        for (int l = 0; l < Ldim; ++l) se += expf(lg[l] - mx);
        float lse = mx + logf(se);
        int lab = label_ids[bs];
        float ll = lg[0];
#pragma unroll
        for (int l = 1; l < Ldim; ++l) ll = (lab == l) ? lg[l] : ll;
        nll = lse - ll;
        cnt = 1.0f;
      }
    }
  }

#pragma unroll
  for (int off = 32; off > 0; off >>= 1) {
    nll += __shfl_down(nll, off, 64);
    cnt += __shfl_down(cnt, off, 64);
  }
  if (lane == 0) { ssm[wid] = nll; csm[wid] = cnt; }
  __syncthreads();
  if (tid == 0) {
    float S = 0.f, C = 0.f;
#pragma unroll
    for (int k = 0; k < 8; ++k) { S += ssm[k]; C += csm[k]; }
    atomicAdd(&accum[0], S);
    atomicAdd(&accum[1], C);
    __threadfence();
    unsigned prev = atomicAdd(counter, 1u);
    if (prev == gridDim.x - 1) {  // last block: all adds visible
      __threadfence();
      float Sf = atomicAdd(&accum[0], 0.0f);
      float Cf = atomicAdd(&accum[1], 0.0f);
      out[0] = Sf / Cf;
    }
  }
}

// ---------------------------------------------------------------------------
// Tiny init kernel: zero the accumulators/counter (ws is not re-poisoned
// between replays; must reset every call). 1 block, runs in ~1 us overlapped
// with nothing -- cheaper than a separate finalizer at the end (dependency-
// free prologue vs serialized epilogue).
// ---------------------------------------------------------------------------
__global__ void init_kernel(float* __restrict__ accum,
                            unsigned* __restrict__ counter) {
  accum[0] = 0.0f;
  accum[1] = 0.0f;
  *counter = 0u;
}

extern "C" void kernel_launch(void* const* d_in, const int* in_sizes, int n_in,
                              void* d_out, int out_size, void* d_ws, size_t ws_size,
                              hipStream_t stream) {
  const float* enc     = (const float*)d_in[0];  // [B,T,H] f32
  const float* W       = (const float*)d_in[1];  // [H,L]   f32
  const float* bias    = (const float*)d_in[2];  // [L]     f32
  const int* attn      = (const int*)d_in[3];    // [B,T]   i32
  const int* ids_lens  = (const int*)d_in[4];    // [B,S]   i32
  const int* label_ids = (const int*)d_in[5];    // [B,S]   i32
  // d_in[6] label_mask is recomputed from ids_lens>0

  float* out = (float*)d_out;  // [1 + B*S]: loss, then argmax as float

  char* ws = (char*)d_ws;
  float* accum      = (float*)ws;           // [2]
  unsigned* counter = (unsigned*)(ws + 128);

  init_kernel<<<1, 1, 0, stream>>>(accum, counter);
  fused_kernel<<<Bdim * 4, 512, 0, stream>>>(enc, W, bias, attn, ids_lens,
                                             label_ids, out, accum, counter);
}

// Round 17
// 32.992 us; speedup vs baseline: 1.1033x; 1.1033x over previous
//
#include <hip/hip_runtime.h>
#include <math.h>

#define Bdim 64
#define Tdim 512
#define Sdim 400
#define Hdim 768
#define Ldim 9

#define QWIN 130        // tokens projected per block: 128 + 2 overlap (len<=3)
#define LPROJ_ROWS 132  // LDS tile rows (padded)

// ---------------------------------------------------------------------------
// DPP 64-lane sum (row_shr 1/2/4/8 + row_bcast 15/31), result in lane 63.
// ---------------------------------------------------------------------------
template <int CTRL>
__device__ __forceinline__ float dpp_add(float x) {
  int y = __builtin_amdgcn_update_dpp(0, __float_as_int(x), CTRL, 0xF, 0xF, false);
  return x + __int_as_float(y);
}
__device__ __forceinline__ float wave_sum63(float x) {
  x = dpp_add<0x111>(x);
  x = dpp_add<0x112>(x);
  x = dpp_add<0x114>(x);
  x = dpp_add<0x118>(x);
  x = dpp_add<0x142>(x);
  x = dpp_add<0x143>(x);
  return x;  // lane 63 = sum of all 64 lanes
}

// ---------------------------------------------------------------------------
// Fused kernel (R14 champion, 33.0 us): 256 blocks = (batch row b, quarter).
//  A: per-row scans in LDS (p2t, wstart, nvalid)
//  B: project tokens q in [part*128, min(part*128+QWIN, nvalid)) into an LDS
//     tile. Valid-only. Waves 0-5 in two groups of 3; per-wave: full-row
//     float4 loads (cache dedups the 3x issue), 3 logits via 36-float
//     register W fragment (R5/R16: bigger fragments cost VGPR/occupancy or
//     silently rematerialize), DPP reduce, lane63 -> LDS. Ping-pong depth-2.
//     launch_bounds(512,2): keeps 2 blocks/CU (R16's (512,1) halved TLP).
//  C: each word with wstart-bucket == part: mean from LDS tile, +bias,
//     argmax -> out, NLL -> block partial (plain store, no atomics).
// Words bucketed by wstart>>7: every word has exactly one owner; its tokens
// (len<=3, start<=511) lie inside the owner's QWIN window.
// ---------------------------------------------------------------------------
__global__ __launch_bounds__(512, 2) void fused_kernel(
    const float* __restrict__ enc, const float* __restrict__ W,
    const float* __restrict__ bias, const int* __restrict__ attn,
    const int* __restrict__ ids_lens, const int* __restrict__ label_ids,
    float* __restrict__ out, float2* __restrict__ partials) {
  int blk = blockIdx.x;
  int b = blk >> 2;
  int part = blk & 3;
  int q0 = part << 7;
  int tid = threadIdx.x;
  int lane = tid & 63, wid = tid >> 6;

  __shared__ int p2t[Tdim];
  __shared__ int wst[Sdim];
  __shared__ float lproj[LPROJ_ROWS][12];
  __shared__ int wsum[8];
  __shared__ int totsm;
  __shared__ float ssm[8], csm[8];

  // ================= phase A: scans =================
  int m = attn[b * Tdim + tid];
  int x = m;
#pragma unroll
  for (int off = 1; off < 64; off <<= 1) {
    int v = __shfl_up(x, off, 64);
    if (lane >= off) x += v;
  }
  if (lane == 63) wsum[wid] = x;
  __syncthreads();
  if (tid < 8) {
    int s = wsum[tid], y = s;
#pragma unroll
    for (int off = 1; off < 8; off <<= 1) {
      int v = __shfl_up(y, off, 64);
      if (tid >= off) y += v;
    }
    wsum[tid] = y - s;
    if (tid == 7) totsm = y;
  }
  __syncthreads();
  x += wsum[wid];
  if (m) p2t[x - 1] = tid;  // q-th valid token -> physical position
  int nv = totsm;
  __syncthreads();  // p2t written; wsum reusable

  int len = (tid < Sdim) ? ids_lens[b * Sdim + tid] : 0;
  int x2 = len;
#pragma unroll
  for (int off = 1; off < 64; off <<= 1) {
    int v = __shfl_up(x2, off, 64);
    if (lane >= off) x2 += v;
  }
  if (lane == 63) wsum[wid] = x2;
  __syncthreads();
  if (tid < 8) {
    int s = wsum[tid], y = s;
#pragma unroll
    for (int off = 1; off < 8; off <<= 1) {
      int v = __shfl_up(y, off, 64);
      if (tid >= off) y += v;
    }
    wsum[tid] = y - s;
  }
  __syncthreads();
  x2 += wsum[wid];
  if (tid < Sdim) wst[tid] = x2 - len;  // exclusive prefix
  __syncthreads();

  // ================= phase B: project this block's token window =================
  int lim = q0 + QWIN;
  if (lim > nv) lim = nv;
  if (wid < 6) {
    int g = (wid >= 3) ? 1 : 0;     // token parity group
    int l0 = (wid - 3 * g) * 3;     // logit slice {l0..l0+2}
    // tokens q = q0 + g + 2k, k = 0..tc-1
    int tc = lim - q0 - g;
    tc = (tc > 0) ? ((tc + 1) >> 1) : 0;

    if (tc > 0) {
      // 36-float register W fragment: h = 4*lane + 256*k + j
      float wf[3][4][3];
#pragma unroll
      for (int k = 0; k < 3; ++k)
#pragma unroll
        for (int j = 0; j < 4; ++j) {
          int h = 4 * lane + 256 * k + j;
#pragma unroll
          for (int c = 0; c < 3; ++c) wf[k][j][c] = W[(size_t)h * Ldim + l0 + c];
        }
      const float4* encb = (const float4*)enc + (size_t)(b << 9) * (Hdim / 4);

      float4 A0, A1, A2, B0, B1, B2;
#define LDK(V0, V1, V2, K)                                                 \
  {                                                                        \
    int t_ = p2t[q0 + g + 2 * (K)];                                        \
    const float4* r_ = encb + (size_t)t_ * (Hdim / 4);                     \
    V0 = r_[lane]; V1 = r_[lane + 64]; V2 = r_[lane + 128];                \
  }
#define PRK(V0, V1, V2, K)                                                 \
  {                                                                        \
    float dd[3];                                                           \
    _Pragma("unroll") for (int c = 0; c < 3; ++c) {                        \
      dd[c] = V0.x * wf[0][0][c] + V0.y * wf[0][1][c] +                    \
              V0.z * wf[0][2][c] + V0.w * wf[0][3][c] +                    \
              V1.x * wf[1][0][c] + V1.y * wf[1][1][c] +                    \
              V1.z * wf[1][2][c] + V1.w * wf[1][3][c] +                    \
              V2.x * wf[2][0][c] + V2.y * wf[2][1][c] +                    \
              V2.z * wf[2][2][c] + V2.w * wf[2][3][c];                     \
      dd[c] = wave_sum63(dd[c]);                                           \
    }                                                                      \
    if (lane == 63) {                                                      \
      int row_ = g + 2 * (K);                                              \
      lproj[row_][l0 + 0] = dd[0];                                         \
      lproj[row_][l0 + 1] = dd[1];                                         \
      lproj[row_][l0 + 2] = dd[2];                                         \
    }                                                                      \
  }
      LDK(A0, A1, A2, 0)
      if (tc > 1) LDK(B0, B1, B2, 1)
      int k = 0;
      for (; k + 2 < tc; k += 2) {
        PRK(A0, A1, A2, k)
        LDK(A0, A1, A2, k + 2)
        PRK(B0, B1, B2, k + 1)
        if (k + 3 < tc) LDK(B0, B1, B2, k + 3)
      }
      PRK(A0, A1, A2, k)
      if (k + 1 < tc) PRK(B0, B1, B2, k + 1)
#undef LDK
#undef PRK
    }
  }
  __syncthreads();

  // ================= phase C: this block's words =================
  float nll = 0.0f, cnt = 0.0f;
  if (tid < Sdim) {
    int st = wst[tid];
    int stc = (st > 511) ? 511 : st;
    if ((stc >> 7) == part) {  // this block owns word tid
      int bs = b * Sdim + tid;
      float sum[Ldim];
#pragma unroll
      for (int l = 0; l < Ldim; ++l) sum[l] = 0.0f;
      if (len > 0) {
        for (int j = 0; j < len; ++j) {
          int q = st + j;
          if (q >= nv) break;
          const float* pr = lproj[q - q0];
#pragma unroll
          for (int l = 0; l < Ldim; ++l) sum[l] += pr[l];
        }
      }
      float inv = (len > 0) ? 1.0f / (float)len : 0.0f;
      float lg[Ldim];
#pragma unroll
      for (int l = 0; l < Ldim; ++l) lg[l] = sum[l] * inv + bias[l];

      int amax = 0;
      float mx = lg[0];
#pragma unroll
      for (int l = 1; l < Ldim; ++l)
        if (lg[l] > mx) { mx = lg[l]; amax = l; }
      out[1 + bs] = (float)amax;

      if (len > 0) {
        float se = 0.0f;
#pragma unroll
        for (int l = 0; l < Ldim; ++l) se += expf(lg[l] - mx);
        float lse = mx + logf(se);
        int lab = label_ids[bs];
        float ll = lg[0];
#pragma unroll
        for (int l = 1; l < Ldim; ++l) ll = (lab == l) ? lg[l] : ll;
        nll = lse - ll;
        cnt = 1.0f;
      }
    }
  }

#pragma unroll
  for (int off = 32; off > 0; off >>= 1) {
    nll += __shfl_down(nll, off, 64);
    cnt += __shfl_down(cnt, off, 64);
  }
  if (lane == 0) { ssm[wid] = nll; csm[wid] = cnt; }
  __syncthreads();
  if (tid == 0) {
    float S = 0.f, C = 0.f;
#pragma unroll
    for (int k = 0; k < 8; ++k) { S += ssm[k]; C += csm[k]; }
    float2 pc; pc.x = S; pc.y = C;
    partials[blk] = pc;  // plain store, no atomics
  }
}

// ---------------------------------------------------------------------------
// Finalize: 1 block, 256 threads: loss = sum(partials.x) / sum(partials.y)
// ---------------------------------------------------------------------------
__global__ __launch_bounds__(256) void final_kernel(
    const float2* __restrict__ partials, float* __restrict__ out) {
  int tid = threadIdx.x;
  float2 pc = partials[tid];  // 256 entries, one per thread
  float s = pc.x, c = pc.y;
#pragma unroll
  for (int off = 32; off > 0; off >>= 1) {
    s += __shfl_down(s, off, 64);
    c += __shfl_down(c, off, 64);
  }
  __shared__ float ss[4], cc[4];
  int wid = tid >> 6, lane = tid & 63;
  if (lane == 0) { ss[wid] = s; cc[wid] = c; }
  __syncthreads();
  if (tid == 0)
    out[0] = (ss[0] + ss[1] + ss[2] + ss[3]) / (cc[0] + cc[1] + cc[2] + cc[3]);
}

extern "C" void kernel_launch(void* const* d_in, const int* in_sizes, int n_in,
                              void* d_out, int out_size, void* d_ws, size_t ws_size,
                              hipStream_t stream) {
  const float* enc     = (const float*)d_in[0];  // [B,T,H] f32
  const float* W       = (const float*)d_in[1];  // [H,L]   f32
  const float* bias    = (const float*)d_in[2];  // [L]     f32
  const int* attn      = (const int*)d_in[3];    // [B,T]   i32
  const int* ids_lens  = (const int*)d_in[4];    // [B,S]   i32
  const int* label_ids = (const int*)d_in[5];    // [B,S]   i32
  // d_in[6] label_mask is recomputed from ids_lens>0

  float* out = (float*)d_out;  // [1 + B*S]: loss, then argmax as float

  float2* partials = (float2*)d_ws;  // 256 float2

  fused_kernel<<<Bdim * 4, 512, 0, stream>>>(enc, W, bias, attn, ids_lens,
                                             label_ids, out, partials);
  final_kernel<<<1, 256, 0, stream>>>(partials, out);
}